// Round 2
// baseline (34295.120 us; speedup 1.0000x reference)
//
#include <hip/hip_runtime.h>
#include <hip/hip_bf16.h>

// ViT-S/16 forward, B=128. Inputs/outputs fp32 (per reference). Internal:
// weights+activations bf16 for MFMA, residual stream fp32, LN/softmax fp32.
// R2: fixed dtype contract (R1 read fp32 buffers as bf16 -> NaN).

#define S_ 197
#define D_ 384
#define BATCH 128

using bf16 = __hip_bfloat16;
typedef __attribute__((ext_vector_type(8))) __bf16 bf16x8;
typedef __attribute__((ext_vector_type(4))) float f32x4;

// fp32 -> bf16 (RN), 4 elements/thread. n must be a multiple of 4.
__global__ __launch_bounds__(256) void k_f2b(const float* __restrict__ src,
                                             bf16* __restrict__ dst, int n4) {
  int i = blockIdx.x * 256 + threadIdx.x;
  if (i >= n4) return;
  float4 v = ((const float4*)src)[i];
  bf16 o[4] = {__float2bfloat16(v.x), __float2bfloat16(v.y),
               __float2bfloat16(v.z), __float2bfloat16(v.w)};
  ((uint2*)dst)[i] = *(uint2*)o;
}

__global__ __launch_bounds__(256) void k_embed_init(const float* __restrict__ cls,
                                                    const float* __restrict__ pos,
                                                    float* __restrict__ h) {
  int idx = blockIdx.x * 256 + threadIdx.x;
  if (idx >= BATCH * S_ * D_) return;
  int d = idx % D_;
  int s = (idx / D_) % S_;
  float v = pos[s * D_ + d];
  if (s == 0) v += cls[d];
  h[idx] = v;
}

__global__ __launch_bounds__(256) void k_patchify(const float* __restrict__ x,
                                                  bf16* __restrict__ patches) {
  int idx = blockIdx.x * 256 + threadIdx.x;
  if (idx >= BATCH * 196 * 768) return;
  int f = idx % 768;
  int n = (idx / 768) % 196;
  int b = idx / (768 * 196);
  int c = f >> 8, rem = f & 255, dy = rem >> 4, dx = rem & 15;
  int py = n / 14, px = n % 14;
  patches[idx] = __float2bfloat16(
      x[(((size_t)b * 3 + c) * 224 + py * 16 + dy) * 224 + px * 16 + dx]);
}

// out[M,N] = X[M,K] @ W[N,K]^T + bias.  Grid: (N/128, M/128), 256 threads.
// MODE 0: out=bf16(v); MODE 1: out=bf16(gelu_exact(v)); MODE 2: res(f32)+=v
// remap!=0 (patch embed): residual row = r + r/196 + 1  (b*196+n -> b*197+1+n)
template <int MODE>
__global__ __launch_bounds__(256, 2) void k_gemm(const bf16* __restrict__ X,
                                                 const bf16* __restrict__ W,
                                                 const float* __restrict__ bias,
                                                 bf16* __restrict__ out,
                                                 float* __restrict__ res,
                                                 int N, int K, int remap) {
  __shared__ __align__(16) __bf16 As[128 * 40];
  __shared__ __align__(16) __bf16 Bs[128 * 40];
  const int tid = threadIdx.x;
  const int m0 = blockIdx.y * 128, n0 = blockIdx.x * 128;
  const int lane = tid & 63, w = tid >> 6;
  const int wr = w >> 1, wc = w & 1;
  const int l16 = lane & 15, quad = lane >> 4;
  f32x4 acc[4][4] = {};

  const int row0 = tid >> 2, colc = (tid & 3) << 3;
  for (int k0 = 0; k0 < K; k0 += 32) {
    *(uint4*)(&As[row0 * 40 + colc]) =
        *(const uint4*)(X + (size_t)(m0 + row0) * K + k0 + colc);
    *(uint4*)(&Bs[row0 * 40 + colc]) =
        *(const uint4*)(W + (size_t)(n0 + row0) * K + k0 + colc);
    *(uint4*)(&As[(row0 + 64) * 40 + colc]) =
        *(const uint4*)(X + (size_t)(m0 + row0 + 64) * K + k0 + colc);
    *(uint4*)(&Bs[(row0 + 64) * 40 + colc]) =
        *(const uint4*)(W + (size_t)(n0 + row0 + 64) * K + k0 + colc);
    __syncthreads();
    bf16x8 av[4], bv[4];
#pragma unroll
    for (int i = 0; i < 4; i++)
      av[i] = *(const bf16x8*)(&As[(wr * 64 + i * 16 + l16) * 40 + quad * 8]);
#pragma unroll
    for (int j = 0; j < 4; j++)
      bv[j] = *(const bf16x8*)(&Bs[(wc * 64 + j * 16 + l16) * 40 + quad * 8]);
#pragma unroll
    for (int i = 0; i < 4; i++)
#pragma unroll
      for (int j = 0; j < 4; j++)
        acc[i][j] = __builtin_amdgcn_mfma_f32_16x16x32_bf16(av[i], bv[j], acc[i][j], 0, 0, 0);
    __syncthreads();
  }

  float bvv[4];
#pragma unroll
  for (int j = 0; j < 4; j++)
    bvv[j] = bias[n0 + wc * 64 + j * 16 + l16];
#pragma unroll
  for (int i = 0; i < 4; i++) {
    const int rbase = m0 + wr * 64 + i * 16 + quad * 4;
#pragma unroll
    for (int j = 0; j < 4; j++) {
      const int col = n0 + wc * 64 + j * 16 + l16;
#pragma unroll
      for (int r = 0; r < 4; r++) {
        float v = acc[i][j][r] + bvv[j];
        int rw = rbase + r;
        if (MODE == 0) {
          out[(size_t)rw * N + col] = __float2bfloat16(v);
        } else if (MODE == 1) {
          float gl = 0.5f * v * (1.f + erff(v * 0.70710678118f));
          out[(size_t)rw * N + col] = __float2bfloat16(gl);
        } else {
          int hr = remap ? (rw + rw / 196 + 1) : rw;
          res[(size_t)hr * N + col] += v;
        }
      }
    }
  }
}

__global__ __launch_bounds__(128) void k_ln(const float* __restrict__ h,
                                            const float* __restrict__ g,
                                            const float* __restrict__ bt,
                                            bf16* __restrict__ xn) {
  const int r = blockIdx.x, t = threadIdx.x;
  const float* row = h + (size_t)r * D_;
  float x0 = row[t], x1 = row[t + 128], x2 = row[t + 256];
  float s = x0 + x1 + x2;
  float q = x0 * x0 + x1 * x1 + x2 * x2;
#pragma unroll
  for (int o = 32; o; o >>= 1) {
    s += __shfl_xor(s, o);
    q += __shfl_xor(q, o);
  }
  __shared__ float rs[2], rq[2];
  if ((t & 63) == 0) { rs[t >> 6] = s; rq[t >> 6] = q; }
  __syncthreads();
  s = rs[0] + rs[1];
  q = rq[0] + rq[1];
  const float mean = s * (1.f / 384.f);
  const float var = q * (1.f / 384.f) - mean * mean;
  const float rstd = rsqrtf(var + 1e-5f);
  bf16* o = xn + (size_t)r * D_;
  o[t] = __float2bfloat16((x0 - mean) * rstd * g[t] + bt[t]);
  o[t + 128] = __float2bfloat16((x1 - mean) * rstd * g[t + 128] + bt[t + 128]);
  o[t + 256] = __float2bfloat16((x2 - mean) * rstd * g[t + 256] + bt[t + 256]);
}

// One block per (b, head). K^T fp32 in LDS (cols pad 197->201, conflict-free);
// V streamed from global (25KB/block, stays L1-hot across the q-loop).
__global__ __launch_bounds__(256) void k_attn(const bf16* __restrict__ qkv,
                                              bf16* __restrict__ ctx) {
  const int bh = blockIdx.x;
  const int b = bh / 6, hd = bh % 6;
  const size_t base = (size_t)b * S_ * 1152;
  const bf16* Qg = qkv + base + hd * 64;
  const bf16* Kg = qkv + base + 384 + hd * 64;
  const bf16* Vg = qkv + base + 768 + hd * 64;
  __shared__ float KT[64 * 201];
  __shared__ float probs[256];
  __shared__ float qrow[64];
  __shared__ float redm[4], reds[4];
  __shared__ float ctxp[4][64];
  const int tid = threadIdx.x, lane = tid & 63, wid = tid >> 6;
  for (int e = tid; e < S_ * 64; e += 256) {
    int j = e >> 6, d = e & 63;
    KT[d * 201 + j] = __bfloat162float(Kg[(size_t)j * 1152 + d]);
  }
  __syncthreads();
  for (int q = 0; q < S_; q++) {
    if (tid < 64) qrow[tid] = 0.125f * __bfloat162float(Qg[(size_t)q * 1152 + tid]);
    __syncthreads();
    float s = -1e30f;
    if (tid < S_) {
      float a = 0.f;
#pragma unroll 16
      for (int d = 0; d < 64; d++) a += qrow[d] * KT[d * 201 + tid];
      s = a;
    }
    float m = s;
#pragma unroll
    for (int o = 32; o; o >>= 1) m = fmaxf(m, __shfl_xor(m, o));
    if (!lane) redm[wid] = m;
    __syncthreads();
    m = fmaxf(fmaxf(redm[0], redm[1]), fmaxf(redm[2], redm[3]));
    float p = (tid < S_) ? __expf(s - m) : 0.f;
    float sm = p;
#pragma unroll
    for (int o = 32; o; o >>= 1) sm += __shfl_xor(sm, o);
    if (!lane) reds[wid] = sm;
    __syncthreads();
    sm = reds[0] + reds[1] + reds[2] + reds[3];
    probs[tid] = p / sm;
    __syncthreads();
    float a = 0.f;
    for (int j = wid; j < S_; j += 4)
      a += probs[j] * __bfloat162float(Vg[(size_t)j * 1152 + lane]);
    ctxp[wid][lane] = a;
    __syncthreads();
    if (tid < 64) {
      float c = ctxp[0][tid] + ctxp[1][tid] + ctxp[2][tid] + ctxp[3][tid];
      ctx[((size_t)b * S_ + q) * D_ + hd * 64 + tid] = __float2bfloat16(c);
    }
    __syncthreads();
  }
}

__global__ __launch_bounds__(128) void k_head(const float* __restrict__ h,
                                              const float* __restrict__ g,
                                              const float* __restrict__ bt,
                                              const float* __restrict__ hw,
                                              float* __restrict__ out) {
  const int b = blockIdx.x, t = threadIdx.x;
  const float* row = h + (size_t)b * S_ * D_;
  float x0 = row[t], x1 = row[t + 128], x2 = row[t + 256];
  float s = x0 + x1 + x2;
  float q = x0 * x0 + x1 * x1 + x2 * x2;
#pragma unroll
  for (int o = 32; o; o >>= 1) {
    s += __shfl_xor(s, o);
    q += __shfl_xor(q, o);
  }
  __shared__ float rs[2], rq[2];
  if ((t & 63) == 0) { rs[t >> 6] = s; rq[t >> 6] = q; }
  __syncthreads();
  s = rs[0] + rs[1];
  q = rq[0] + rq[1];
  const float mean = s * (1.f / 384.f);
  const float var = q * (1.f / 384.f) - mean * mean;
  const float rstd = rsqrtf(var + 1e-5f);
  __shared__ float clsn[384];
  clsn[t] = (x0 - mean) * rstd * g[t] + bt[t];
  clsn[t + 128] = (x1 - mean) * rstd * g[t + 128] + bt[t + 128];
  clsn[t + 256] = (x2 - mean) * rstd * g[t + 256] + bt[t + 256];
  __syncthreads();
  if (t < 100) {
    const float* wr = hw + (size_t)t * D_;
    float a = 0.f;
    for (int d = 0; d < 384; d++) a += clsn[d] * wr[d];
    out[b * 100 + t] = a;
  }
}

extern "C" void kernel_launch(void* const* d_in, const int* in_sizes, int n_in,
                              void* d_out, int out_size, void* d_ws, size_t ws_size,
                              hipStream_t stream) {
  (void)in_sizes; (void)n_in; (void)out_size; (void)ws_size;
  const float* x       = (const float*)d_in[0];
  const float* patch_w = (const float*)d_in[1];
  const float* patch_b = (const float*)d_in[2];
  const float* cls_tok = (const float*)d_in[3];
  const float* pos_emb = (const float*)d_in[4];
  const float* ln1_g   = (const float*)d_in[5];
  const float* ln1_b   = (const float*)d_in[6];
  const float* qkv_w   = (const float*)d_in[7];
  const float* qkv_b   = (const float*)d_in[8];
  const float* out_w   = (const float*)d_in[9];
  const float* out_b   = (const float*)d_in[10];
  const float* ln2_g   = (const float*)d_in[11];
  const float* ln2_b   = (const float*)d_in[12];
  const float* fc1_w   = (const float*)d_in[13];
  const float* fc1_b   = (const float*)d_in[14];
  const float* fc2_w   = (const float*)d_in[15];
  const float* fc2_b   = (const float*)d_in[16];
  const float* lnf_g   = (const float*)d_in[17];
  const float* lnf_b   = (const float*)d_in[18];
  const float* head_w  = (const float*)d_in[19];
  float* out = (float*)d_out;

  const size_t R = (size_t)BATCH * S_;  // 25216 token rows
  char* p = (char*)d_ws;
  float* h  = (float*)p; p += R * 384 * 4;       // fp32 residual
  bf16* xn  = (bf16*)p;  p += R * 384 * 2;       // LN output
  bf16* u   = (bf16*)p;  p += R * 1536 * 2;      // union: qkvb|ctxb / hid / patches
  bf16* qkvb = u;                                 // R*1152
  bf16* ctxb = u + R * 1152;                      // R*384
  bf16* hidb = u;                                 // R*1536 (qkv/ctx dead by then)
  bf16* patches = u;                              // 25088*768 (pre-loop only)
  bf16* wb  = (bf16*)p;                           // bf16 weights
  bf16* patch_wb = wb;                            // 768*384
  bf16* qkv_wb   = patch_wb + 294912;             // 12*1152*384
  bf16* out_wb   = qkv_wb + 5308416;              // 12*384*384
  bf16* fc1_wb   = out_wb + 1769472;              // 12*1536*384
  bf16* fc2_wb   = fc1_wb + 7077888;              // 12*384*1536

  // weight conversion fp32 -> bf16 (same work every launch; graph-safe)
  k_f2b<<<dim3((294912 / 4 + 255) / 256), dim3(256), 0, stream>>>(patch_w, patch_wb, 294912 / 4);
  k_f2b<<<dim3((5308416 / 4 + 255) / 256), dim3(256), 0, stream>>>(qkv_w, qkv_wb, 5308416 / 4);
  k_f2b<<<dim3((1769472 / 4 + 255) / 256), dim3(256), 0, stream>>>(out_w, out_wb, 1769472 / 4);
  k_f2b<<<dim3((7077888 / 4 + 255) / 256), dim3(256), 0, stream>>>(fc1_w, fc1_wb, 7077888 / 4);
  k_f2b<<<dim3((7077888 / 4 + 255) / 256), dim3(256), 0, stream>>>(fc2_w, fc2_wb, 7077888 / 4);

  k_embed_init<<<dim3((BATCH * S_ * D_) / 256), dim3(256), 0, stream>>>(cls_tok, pos_emb, h);
  k_patchify<<<dim3((BATCH * 196 * 768) / 256), dim3(256), 0, stream>>>(x, patches);
  // tok = patches @ patch_w^T + patch_b, accumulated into h (row remap b*196+n -> b*197+1+n)
  k_gemm<2><<<dim3(3, 196), dim3(256), 0, stream>>>(patches, patch_wb, patch_b, nullptr, h, 384, 768, 1);

  for (int i = 0; i < 12; i++) {
    k_ln<<<dim3((unsigned)R), dim3(128), 0, stream>>>(h, ln1_g + i * 384, ln1_b + i * 384, xn);
    k_gemm<0><<<dim3(9, 197), dim3(256), 0, stream>>>(xn, qkv_wb + (size_t)i * 1152 * 384,
                                                      qkv_b + i * 1152, qkvb, nullptr, 1152, 384, 0);
    k_attn<<<dim3(768), dim3(256), 0, stream>>>(qkvb, ctxb);
    k_gemm<2><<<dim3(3, 197), dim3(256), 0, stream>>>(ctxb, out_wb + (size_t)i * 384 * 384,
                                                      out_b + i * 384, nullptr, h, 384, 384, 0);
    k_ln<<<dim3((unsigned)R), dim3(128), 0, stream>>>(h, ln2_g + i * 384, ln2_b + i * 384, xn);
    k_gemm<1><<<dim3(12, 197), dim3(256), 0, stream>>>(xn, fc1_wb + (size_t)i * 1536 * 384,
                                                       fc1_b + i * 1536, hidb, nullptr, 1536, 384, 0);
    k_gemm<2><<<dim3(3, 197), dim3(256), 0, stream>>>(hidb, fc2_wb + (size_t)i * 384 * 1536,
                                                      fc2_b + i * 384, nullptr, h, 384, 1536, 0);
  }
  k_head<<<dim3(128), dim3(128), 0, stream>>>(h, lnf_g, lnf_b, head_w, out);
}

// Round 3
// 3892.570 us; speedup vs baseline: 8.8104x; 8.8104x over previous
//
#include <hip/hip_runtime.h>
#include <hip/hip_bf16.h>

// ViT-S/16 forward, B=128. Inputs/outputs fp32 (per reference). Internal:
// weights+activations bf16 for MFMA, residual stream fp32, LN/softmax fp32.
// R3: MFMA flash-attention (barrier-free band loop). R2's k_attn was 93% of
// runtime (2.67 ms x12, barrier/latency-bound at 197 serialized iterations).

#define S_ 197
#define D_ 384
#define BATCH 128

using bf16 = __hip_bfloat16;
typedef __attribute__((ext_vector_type(8))) __bf16 bf16x8;
typedef __attribute__((ext_vector_type(4))) float f32x4;

// fp32 -> bf16 (RN), 4 elements/thread. n must be a multiple of 4.
__global__ __launch_bounds__(256) void k_f2b(const float* __restrict__ src,
                                             bf16* __restrict__ dst, int n4) {
  int i = blockIdx.x * 256 + threadIdx.x;
  if (i >= n4) return;
  float4 v = ((const float4*)src)[i];
  bf16 o[4] = {__float2bfloat16(v.x), __float2bfloat16(v.y),
               __float2bfloat16(v.z), __float2bfloat16(v.w)};
  ((uint2*)dst)[i] = *(uint2*)o;
}

__global__ __launch_bounds__(256) void k_embed_init(const float* __restrict__ cls,
                                                    const float* __restrict__ pos,
                                                    float* __restrict__ h) {
  int idx = blockIdx.x * 256 + threadIdx.x;
  if (idx >= BATCH * S_ * D_) return;
  int d = idx % D_;
  int s = (idx / D_) % S_;
  float v = pos[s * D_ + d];
  if (s == 0) v += cls[d];
  h[idx] = v;
}

__global__ __launch_bounds__(256) void k_patchify(const float* __restrict__ x,
                                                  bf16* __restrict__ patches) {
  int idx = blockIdx.x * 256 + threadIdx.x;
  if (idx >= BATCH * 196 * 768) return;
  int f = idx % 768;
  int n = (idx / 768) % 196;
  int b = idx / (768 * 196);
  int c = f >> 8, rem = f & 255, dy = rem >> 4, dx = rem & 15;
  int py = n / 14, px = n % 14;
  patches[idx] = __float2bfloat16(
      x[(((size_t)b * 3 + c) * 224 + py * 16 + dy) * 224 + px * 16 + dx]);
}

// out[M,N] = X[M,K] @ W[N,K]^T + bias.  Grid: (N/128, M/128), 256 threads.
// MODE 0: out=bf16(v); MODE 1: out=bf16(gelu_exact(v)); MODE 2: res(f32)+=v
// remap!=0 (patch embed): residual row = r + r/196 + 1  (b*196+n -> b*197+1+n)
template <int MODE>
__global__ __launch_bounds__(256, 2) void k_gemm(const bf16* __restrict__ X,
                                                 const bf16* __restrict__ W,
                                                 const float* __restrict__ bias,
                                                 bf16* __restrict__ out,
                                                 float* __restrict__ res,
                                                 int N, int K, int remap) {
  __shared__ __align__(16) __bf16 As[128 * 40];
  __shared__ __align__(16) __bf16 Bs[128 * 40];
  const int tid = threadIdx.x;
  const int m0 = blockIdx.y * 128, n0 = blockIdx.x * 128;
  const int lane = tid & 63, w = tid >> 6;
  const int wr = w >> 1, wc = w & 1;
  const int l16 = lane & 15, quad = lane >> 4;
  f32x4 acc[4][4] = {};

  const int row0 = tid >> 2, colc = (tid & 3) << 3;
  for (int k0 = 0; k0 < K; k0 += 32) {
    *(uint4*)(&As[row0 * 40 + colc]) =
        *(const uint4*)(X + (size_t)(m0 + row0) * K + k0 + colc);
    *(uint4*)(&Bs[row0 * 40 + colc]) =
        *(const uint4*)(W + (size_t)(n0 + row0) * K + k0 + colc);
    *(uint4*)(&As[(row0 + 64) * 40 + colc]) =
        *(const uint4*)(X + (size_t)(m0 + row0 + 64) * K + k0 + colc);
    *(uint4*)(&Bs[(row0 + 64) * 40 + colc]) =
        *(const uint4*)(W + (size_t)(n0 + row0 + 64) * K + k0 + colc);
    __syncthreads();
    bf16x8 av[4], bv[4];
#pragma unroll
    for (int i = 0; i < 4; i++)
      av[i] = *(const bf16x8*)(&As[(wr * 64 + i * 16 + l16) * 40 + quad * 8]);
#pragma unroll
    for (int j = 0; j < 4; j++)
      bv[j] = *(const bf16x8*)(&Bs[(wc * 64 + j * 16 + l16) * 40 + quad * 8]);
#pragma unroll
    for (int i = 0; i < 4; i++)
#pragma unroll
      for (int j = 0; j < 4; j++)
        acc[i][j] = __builtin_amdgcn_mfma_f32_16x16x32_bf16(av[i], bv[j], acc[i][j], 0, 0, 0);
    __syncthreads();
  }

  float bvv[4];
#pragma unroll
  for (int j = 0; j < 4; j++)
    bvv[j] = bias[n0 + wc * 64 + j * 16 + l16];
#pragma unroll
  for (int i = 0; i < 4; i++) {
    const int rbase = m0 + wr * 64 + i * 16 + quad * 4;
#pragma unroll
    for (int j = 0; j < 4; j++) {
      const int col = n0 + wc * 64 + j * 16 + l16;
#pragma unroll
      for (int r = 0; r < 4; r++) {
        float v = acc[i][j][r] + bvv[j];
        int rw = rbase + r;
        if (MODE == 0) {
          out[(size_t)rw * N + col] = __float2bfloat16(v);
        } else if (MODE == 1) {
          float gl = 0.5f * v * (1.f + erff(v * 0.70710678118f));
          out[(size_t)rw * N + col] = __float2bfloat16(gl);
        } else {
          int hr = remap ? (rw + rw / 196 + 1) : rw;
          res[(size_t)hr * N + col] += v;
        }
      }
    }
  }
}

__global__ __launch_bounds__(128) void k_ln(const float* __restrict__ h,
                                            const float* __restrict__ g,
                                            const float* __restrict__ bt,
                                            bf16* __restrict__ xn) {
  const int r = blockIdx.x, t = threadIdx.x;
  const float* row = h + (size_t)r * D_;
  float x0 = row[t], x1 = row[t + 128], x2 = row[t + 256];
  float s = x0 + x1 + x2;
  float q = x0 * x0 + x1 * x1 + x2 * x2;
#pragma unroll
  for (int o = 32; o; o >>= 1) {
    s += __shfl_xor(s, o);
    q += __shfl_xor(q, o);
  }
  __shared__ float rs[2], rq[2];
  if ((t & 63) == 0) { rs[t >> 6] = s; rq[t >> 6] = q; }
  __syncthreads();
  s = rs[0] + rs[1];
  q = rq[0] + rq[1];
  const float mean = s * (1.f / 384.f);
  const float var = q * (1.f / 384.f) - mean * mean;
  const float rstd = rsqrtf(var + 1e-5f);
  bf16* o = xn + (size_t)r * D_;
  o[t] = __float2bfloat16((x0 - mean) * rstd * g[t] + bt[t]);
  o[t + 128] = __float2bfloat16((x1 - mean) * rstd * g[t + 128] + bt[t + 128]);
  o[t + 256] = __float2bfloat16((x2 - mean) * rstd * g[t + 256] + bt[t + 256]);
}

// MFMA flash attention. One block per (b, head), 4 waves. Each wave owns
// q-bands {w, w+4, w+8, ...} of 16 rows: QK^T (13 col-tiles, K=64) -> masked
// softmax (band-local, shuffle over l16 only) -> P band to LDS (C->A layout
// round-trip) -> P@V via LDS V^T. No __syncthreads after staging.
__global__ __launch_bounds__(256) void k_attn(const bf16* __restrict__ qkv,
                                              bf16* __restrict__ ctx) {
  const int bh = blockIdx.x;
  const int b = bh / 6, hd = bh % 6;
  const bf16* Qg = qkv + (size_t)b * S_ * 1152 + hd * 64;
  const bf16* Kg = Qg + 384;
  const bf16* Vg = Qg + 768;
  // Vt[d][k] = V[k][d]; stride 232 (116 dw -> 2-way bank alias = free)
  __shared__ __align__(16) __bf16 Vt[64 * 232];
  __shared__ __align__(16) __bf16 Ps[4][16 * 232];
  const int tid = threadIdx.x;
  const int lane = tid & 63, w = tid >> 6;
  const int l16 = lane & 15, quad = lane >> 4;
  const __bf16 z = (__bf16)0.0f;

  // zero Vt pad cols (k = 197..231)
  for (int i = tid; i < 64 * 35; i += 256) {
    int d = i / 35, k = 197 + i % 35;
    Vt[d * 232 + k] = z;
  }
  // stage V transposed
  for (int i = tid; i < S_ * 64; i += 256) {
    int k = i >> 6, d = i & 63;
    Vt[d * 232 + k] = *(const __bf16*)&Vg[(size_t)k * 1152 + d];
  }
  // zero own Ps pad cols (208..231)
  for (int i = lane; i < 16 * 24; i += 64) {
    int r = i / 24, c = 208 + i % 24;
    Ps[w][r * 232 + c] = z;
  }
  __syncthreads();

  const bf16x8 zf = {};
  for (int band = w; band < 13; band += 4) {
    // Q A-fragments (row = band*16 + l16), predicated on row < 197
    const int qrow = band * 16 + l16;
    bf16x8 aq0 = zf, aq1 = zf;
    if (qrow < S_) {
      aq0 = *(const bf16x8*)(Qg + (size_t)qrow * 1152 + quad * 8);
      aq1 = *(const bf16x8*)(Qg + (size_t)qrow * 1152 + 32 + quad * 8);
    }
    // scores: 13 col-tiles of 16
    f32x4 sc[13];
#pragma unroll
    for (int t = 0; t < 13; t++) {
      const int krow = t * 16 + l16;
      bf16x8 bk0 = zf, bk1 = zf;
      if (krow < S_) {
        bk0 = *(const bf16x8*)(Kg + (size_t)krow * 1152 + quad * 8);
        bk1 = *(const bf16x8*)(Kg + (size_t)krow * 1152 + 32 + quad * 8);
      }
      f32x4 a = {};
      a = __builtin_amdgcn_mfma_f32_16x16x32_bf16(aq0, bk0, a, 0, 0, 0);
      a = __builtin_amdgcn_mfma_f32_16x16x32_bf16(aq1, bk1, a, 0, 0, 0);
      sc[t] = a;
    }
    // scale 1/sqrt(64), mask pad cols (192+l16 >= 197)
#pragma unroll
    for (int t = 0; t < 13; t++)
#pragma unroll
      for (int r = 0; r < 4; r++) sc[t][r] *= 0.125f;
    if (l16 >= 5) {
#pragma unroll
      for (int r = 0; r < 4; r++) sc[12][r] = -1e30f;
    }
    // row max (across 13 tiles in-reg, then across the 16 lanes of this quad)
    f32x4 mx = sc[0];
#pragma unroll
    for (int t = 1; t < 13; t++)
#pragma unroll
      for (int r = 0; r < 4; r++) mx[r] = fmaxf(mx[r], sc[t][r]);
#pragma unroll
    for (int o = 1; o < 16; o <<= 1)
#pragma unroll
      for (int r = 0; r < 4; r++) mx[r] = fmaxf(mx[r], __shfl_xor(mx[r], o));
    // exp + row sum
    f32x4 sum = {};
#pragma unroll
    for (int t = 0; t < 13; t++)
#pragma unroll
      for (int r = 0; r < 4; r++) {
        float p = __expf(sc[t][r] - mx[r]);
        sc[t][r] = p;
        sum[r] += p;
      }
#pragma unroll
    for (int o = 1; o < 16; o <<= 1)
#pragma unroll
      for (int r = 0; r < 4; r++) sum[r] += __shfl_xor(sum[r], o);
    f32x4 rinv;
#pragma unroll
    for (int r = 0; r < 4; r++) rinv[r] = 1.0f / sum[r];
    // write unnormalized P band (C layout -> LDS); pad cols 197..207 are
    // exact zeros (exp(-1e30-m) underflows to 0)
#pragma unroll
    for (int t = 0; t < 13; t++)
#pragma unroll
      for (int r = 0; r < 4; r++)
        Ps[w][(quad * 4 + r) * 232 + t * 16 + l16] = (__bf16)sc[t][r];
    // P @ V: out cols d = c*16 + l16, k over 224 (7 steps of 32)
    f32x4 oacc[4] = {};
#pragma unroll
    for (int ks = 0; ks < 7; ks++) {
      bf16x8 pa = *(const bf16x8*)&Ps[w][l16 * 232 + ks * 32 + quad * 8];
#pragma unroll
      for (int c = 0; c < 4; c++) {
        bf16x8 bv = *(const bf16x8*)&Vt[(c * 16 + l16) * 232 + ks * 32 + quad * 8];
        oacc[c] = __builtin_amdgcn_mfma_f32_16x16x32_bf16(pa, bv, oacc[c], 0, 0, 0);
      }
    }
    // epilogue: rows band*16 + quad*4 + r (guarded), cols hd*64 + c*16 + l16
    const int orow = band * 16 + quad * 4;
#pragma unroll
    for (int c = 0; c < 4; c++)
#pragma unroll
      for (int r = 0; r < 4; r++) {
        const int rw = orow + r;
        if (rw < S_)
          ctx[((size_t)b * S_ + rw) * D_ + hd * 64 + c * 16 + l16] =
              __float2bfloat16(oacc[c][r] * rinv[r]);
      }
  }
}

__global__ __launch_bounds__(128) void k_head(const float* __restrict__ h,
                                              const float* __restrict__ g,
                                              const float* __restrict__ bt,
                                              const float* __restrict__ hw,
                                              float* __restrict__ out) {
  const int b = blockIdx.x, t = threadIdx.x;
  const float* row = h + (size_t)b * S_ * D_;
  float x0 = row[t], x1 = row[t + 128], x2 = row[t + 256];
  float s = x0 + x1 + x2;
  float q = x0 * x0 + x1 * x1 + x2 * x2;
#pragma unroll
  for (int o = 32; o; o >>= 1) {
    s += __shfl_xor(s, o);
    q += __shfl_xor(q, o);
  }
  __shared__ float rs[2], rq[2];
  if ((t & 63) == 0) { rs[t >> 6] = s; rq[t >> 6] = q; }
  __syncthreads();
  s = rs[0] + rs[1];
  q = rq[0] + rq[1];
  const float mean = s * (1.f / 384.f);
  const float var = q * (1.f / 384.f) - mean * mean;
  const float rstd = rsqrtf(var + 1e-5f);
  __shared__ float clsn[384];
  clsn[t] = (x0 - mean) * rstd * g[t] + bt[t];
  clsn[t + 128] = (x1 - mean) * rstd * g[t + 128] + bt[t + 128];
  clsn[t + 256] = (x2 - mean) * rstd * g[t + 256] + bt[t + 256];
  __syncthreads();
  if (t < 100) {
    const float* wr = hw + (size_t)t * D_;
    float a = 0.f;
    for (int d = 0; d < 384; d++) a += clsn[d] * wr[d];
    out[b * 100 + t] = a;
  }
}

extern "C" void kernel_launch(void* const* d_in, const int* in_sizes, int n_in,
                              void* d_out, int out_size, void* d_ws, size_t ws_size,
                              hipStream_t stream) {
  (void)in_sizes; (void)n_in; (void)out_size; (void)ws_size;
  const float* x       = (const float*)d_in[0];
  const float* patch_w = (const float*)d_in[1];
  const float* patch_b = (const float*)d_in[2];
  const float* cls_tok = (const float*)d_in[3];
  const float* pos_emb = (const float*)d_in[4];
  const float* ln1_g   = (const float*)d_in[5];
  const float* ln1_b   = (const float*)d_in[6];
  const float* qkv_w   = (const float*)d_in[7];
  const float* qkv_b   = (const float*)d_in[8];
  const float* out_w   = (const float*)d_in[9];
  const float* out_b   = (const float*)d_in[10];
  const float* ln2_g   = (const float*)d_in[11];
  const float* ln2_b   = (const float*)d_in[12];
  const float* fc1_w   = (const float*)d_in[13];
  const float* fc1_b   = (const float*)d_in[14];
  const float* fc2_w   = (const float*)d_in[15];
  const float* fc2_b   = (const float*)d_in[16];
  const float* lnf_g   = (const float*)d_in[17];
  const float* lnf_b   = (const float*)d_in[18];
  const float* head_w  = (const float*)d_in[19];
  float* out = (float*)d_out;

  const size_t R = (size_t)BATCH * S_;  // 25216 token rows
  char* p = (char*)d_ws;
  float* h  = (float*)p; p += R * 384 * 4;       // fp32 residual
  bf16* xn  = (bf16*)p;  p += R * 384 * 2;       // LN output
  bf16* u   = (bf16*)p;  p += R * 1536 * 2;      // union: qkvb|ctxb / hid / patches
  bf16* qkvb = u;                                 // R*1152
  bf16* ctxb = u + R * 1152;                      // R*384
  bf16* hidb = u;                                 // R*1536 (qkv/ctx dead by then)
  bf16* patches = u;                              // 25088*768 (pre-loop only)
  bf16* wb  = (bf16*)p;                           // bf16 weights
  bf16* patch_wb = wb;                            // 768*384
  bf16* qkv_wb   = patch_wb + 294912;             // 12*1152*384
  bf16* out_wb   = qkv_wb + 5308416;              // 12*384*384
  bf16* fc1_wb   = out_wb + 1769472;              // 12*1536*384
  bf16* fc2_wb   = fc1_wb + 7077888;              // 12*384*1536

  // weight conversion fp32 -> bf16 (same work every launch; graph-safe)
  k_f2b<<<dim3((294912 / 4 + 255) / 256), dim3(256), 0, stream>>>(patch_w, patch_wb, 294912 / 4);
  k_f2b<<<dim3((5308416 / 4 + 255) / 256), dim3(256), 0, stream>>>(qkv_w, qkv_wb, 5308416 / 4);
  k_f2b<<<dim3((1769472 / 4 + 255) / 256), dim3(256), 0, stream>>>(out_w, out_wb, 1769472 / 4);
  k_f2b<<<dim3((7077888 / 4 + 255) / 256), dim3(256), 0, stream>>>(fc1_w, fc1_wb, 7077888 / 4);
  k_f2b<<<dim3((7077888 / 4 + 255) / 256), dim3(256), 0, stream>>>(fc2_w, fc2_wb, 7077888 / 4);

  k_embed_init<<<dim3((BATCH * S_ * D_) / 256), dim3(256), 0, stream>>>(cls_tok, pos_emb, h);
  k_patchify<<<dim3((BATCH * 196 * 768) / 256), dim3(256), 0, stream>>>(x, patches);
  // tok = patches @ patch_w^T + patch_b, accumulated into h (row remap b*196+n -> b*197+1+n)
  k_gemm<2><<<dim3(3, 196), dim3(256), 0, stream>>>(patches, patch_wb, patch_b, nullptr, h, 384, 768, 1);

  for (int i = 0; i < 12; i++) {
    k_ln<<<dim3((unsigned)R), dim3(128), 0, stream>>>(h, ln1_g + i * 384, ln1_b + i * 384, xn);
    k_gemm<0><<<dim3(9, 197), dim3(256), 0, stream>>>(xn, qkv_wb + (size_t)i * 1152 * 384,
                                                      qkv_b + i * 1152, qkvb, nullptr, 1152, 384, 0);
    k_attn<<<dim3(768), dim3(256), 0, stream>>>(qkvb, ctxb);
    k_gemm<2><<<dim3(3, 197), dim3(256), 0, stream>>>(ctxb, out_wb + (size_t)i * 384 * 384,
                                                      out_b + i * 384, nullptr, h, 384, 384, 0);
    k_ln<<<dim3((unsigned)R), dim3(128), 0, stream>>>(h, ln2_g + i * 384, ln2_b + i * 384, xn);
    k_gemm<1><<<dim3(12, 197), dim3(256), 0, stream>>>(xn, fc1_wb + (size_t)i * 1536 * 384,
                                                       fc1_b + i * 1536, hidb, nullptr, 1536, 384, 0);
    k_gemm<2><<<dim3(3, 197), dim3(256), 0, stream>>>(hidb, fc2_wb + (size_t)i * 384 * 1536,
                                                      fc2_b + i * 384, nullptr, h, 384, 1536, 0);
  }
  k_head<<<dim3(128), dim3(128), 0, stream>>>(h, lnf_g, lnf_b, head_w, out);
}

// Round 4
// 3706.213 us; speedup vs baseline: 9.2534x; 1.0503x over previous
//
#include <hip/hip_runtime.h>
#include <hip/hip_bf16.h>

// ViT-S/16 forward, B=128. Inputs/outputs fp32 (per reference). Internal:
// weights+activations bf16 for MFMA, residual stream fp32, LN/softmax fp32.
// R4: k_gemm staging via global_load_lds width=16 (m97 ladder: 517->874 TF),
// unpadded 128x32 LDS tiles (async-LDS contract forbids padding), 16KB LDS,
// launch_bounds(256,3). R3 GEMMs were latency-bound (Mfma 13%, HBM 27%).

#define S_ 197
#define D_ 384
#define BATCH 128

using bf16 = __hip_bfloat16;
typedef __attribute__((ext_vector_type(8))) __bf16 bf16x8;
typedef __attribute__((ext_vector_type(4))) float f32x4;

#if __has_builtin(__builtin_amdgcn_global_load_lds)
#define HAVE_GLL 1
__device__ __forceinline__ void gll16(const bf16* g, __bf16* l) {
  __builtin_amdgcn_global_load_lds(
      (const __attribute__((address_space(1))) void*)g,
      (__attribute__((address_space(3))) void*)l, 16, 0, 0);
}
#else
#define HAVE_GLL 0
#endif

// fp32 -> bf16 (RN), 4 elements/thread. n must be a multiple of 4.
__global__ __launch_bounds__(256) void k_f2b(const float* __restrict__ src,
                                             bf16* __restrict__ dst, int n4) {
  int i = blockIdx.x * 256 + threadIdx.x;
  if (i >= n4) return;
  float4 v = ((const float4*)src)[i];
  bf16 o[4] = {__float2bfloat16(v.x), __float2bfloat16(v.y),
               __float2bfloat16(v.z), __float2bfloat16(v.w)};
  ((uint2*)dst)[i] = *(uint2*)o;
}

__global__ __launch_bounds__(256) void k_embed_init(const float* __restrict__ cls,
                                                    const float* __restrict__ pos,
                                                    float* __restrict__ h) {
  int idx = blockIdx.x * 256 + threadIdx.x;
  if (idx >= BATCH * S_ * D_) return;
  int d = idx % D_;
  int s = (idx / D_) % S_;
  float v = pos[s * D_ + d];
  if (s == 0) v += cls[d];
  h[idx] = v;
}

__global__ __launch_bounds__(256) void k_patchify(const float* __restrict__ x,
                                                  bf16* __restrict__ patches) {
  int idx = blockIdx.x * 256 + threadIdx.x;
  if (idx >= BATCH * 196 * 768) return;
  int f = idx % 768;
  int n = (idx / 768) % 196;
  int b = idx / (768 * 196);
  int c = f >> 8, rem = f & 255, dy = rem >> 4, dx = rem & 15;
  int py = n / 14, px = n % 14;
  patches[idx] = __float2bfloat16(
      x[(((size_t)b * 3 + c) * 224 + py * 16 + dy) * 224 + px * 16 + dx]);
}

// out[M,N] = X[M,K] @ W[N,K]^T + bias.  Grid: (N/128, M/128), 256 threads.
// MODE 0: out=bf16(v); MODE 1: out=bf16(gelu_exact(v)); MODE 2: res(f32)+=v
// remap!=0 (patch embed): residual row = r + r/196 + 1  (b*196+n -> b*197+1+n)
// Staging: global_load_lds 16B; wave w stages A/B rows 32w..32w+31 via 2
// instructions each (64 lanes x 16B = 16 rows of 64B per instruction).
template <int MODE>
__global__ __launch_bounds__(256, 3) void k_gemm(const bf16* __restrict__ X,
                                                 const bf16* __restrict__ W,
                                                 const float* __restrict__ bias,
                                                 bf16* __restrict__ out,
                                                 float* __restrict__ res,
                                                 int N, int K, int remap) {
  __shared__ __align__(16) __bf16 As[128 * 32];
  __shared__ __align__(16) __bf16 Bs[128 * 32];
  const int tid = threadIdx.x;
  const int m0 = blockIdx.y * 128, n0 = blockIdx.x * 128;
  const int lane = tid & 63, w = tid >> 6;
  const int wr = w >> 1, wc = w & 1;
  const int l16 = lane & 15, quad = lane >> 4;
  f32x4 acc[4][4] = {};

  // per-lane global source: row = 32w + 16q + lane/4, bytes (lane&3)*16
  const int srow = w * 32 + (lane >> 2);
  const int scol = (lane & 3) * 8;  // element offset within 32-elem row
  const bf16* Ag = X + (size_t)(m0 + srow) * K + scol;
  const bf16* Bg = W + (size_t)(n0 + srow) * K + scol;
  __bf16* AsW = As + w * 32 * 32;  // wave-uniform LDS base (lane*16B implicit)
  __bf16* BsW = Bs + w * 32 * 32;

  for (int k0 = 0; k0 < K; k0 += 32) {
#if HAVE_GLL
    gll16(Ag + k0, AsW);
    gll16(Ag + k0 + (size_t)16 * K, AsW + 16 * 32);
    gll16(Bg + k0, BsW);
    gll16(Bg + k0 + (size_t)16 * K, BsW + 16 * 32);
#else
    *(uint4*)(AsW + (lane >> 2) * 32 + scol) = *(const uint4*)(Ag + k0);
    *(uint4*)(AsW + (16 + (lane >> 2)) * 32 + scol) = *(const uint4*)(Ag + k0 + (size_t)16 * K);
    *(uint4*)(BsW + (lane >> 2) * 32 + scol) = *(const uint4*)(Bg + k0);
    *(uint4*)(BsW + (16 + (lane >> 2)) * 32 + scol) = *(const uint4*)(Bg + k0 + (size_t)16 * K);
#endif
    __syncthreads();
    bf16x8 av[4], bv[4];
#pragma unroll
    for (int i = 0; i < 4; i++)
      av[i] = *(const bf16x8*)(&As[(wr * 64 + i * 16 + l16) * 32 + quad * 8]);
#pragma unroll
    for (int j = 0; j < 4; j++)
      bv[j] = *(const bf16x8*)(&Bs[(wc * 64 + j * 16 + l16) * 32 + quad * 8]);
#pragma unroll
    for (int i = 0; i < 4; i++)
#pragma unroll
      for (int j = 0; j < 4; j++)
        acc[i][j] = __builtin_amdgcn_mfma_f32_16x16x32_bf16(av[i], bv[j], acc[i][j], 0, 0, 0);
    __syncthreads();
  }

  float bvv[4];
#pragma unroll
  for (int j = 0; j < 4; j++)
    bvv[j] = bias[n0 + wc * 64 + j * 16 + l16];
#pragma unroll
  for (int i = 0; i < 4; i++) {
    const int rbase = m0 + wr * 64 + i * 16 + quad * 4;
#pragma unroll
    for (int j = 0; j < 4; j++) {
      const int col = n0 + wc * 64 + j * 16 + l16;
#pragma unroll
      for (int r = 0; r < 4; r++) {
        float v = acc[i][j][r] + bvv[j];
        int rw = rbase + r;
        if (MODE == 0) {
          out[(size_t)rw * N + col] = __float2bfloat16(v);
        } else if (MODE == 1) {
          float gl = 0.5f * v * (1.f + erff(v * 0.70710678118f));
          out[(size_t)rw * N + col] = __float2bfloat16(gl);
        } else {
          int hr = remap ? (rw + rw / 196 + 1) : rw;
          res[(size_t)hr * N + col] += v;
        }
      }
    }
  }
}

__global__ __launch_bounds__(128) void k_ln(const float* __restrict__ h,
                                            const float* __restrict__ g,
                                            const float* __restrict__ bt,
                                            bf16* __restrict__ xn) {
  const int r = blockIdx.x, t = threadIdx.x;
  const float* row = h + (size_t)r * D_;
  float x0 = row[t], x1 = row[t + 128], x2 = row[t + 256];
  float s = x0 + x1 + x2;
  float q = x0 * x0 + x1 * x1 + x2 * x2;
#pragma unroll
  for (int o = 32; o; o >>= 1) {
    s += __shfl_xor(s, o);
    q += __shfl_xor(q, o);
  }
  __shared__ float rs[2], rq[2];
  if ((t & 63) == 0) { rs[t >> 6] = s; rq[t >> 6] = q; }
  __syncthreads();
  s = rs[0] + rs[1];
  q = rq[0] + rq[1];
  const float mean = s * (1.f / 384.f);
  const float var = q * (1.f / 384.f) - mean * mean;
  const float rstd = rsqrtf(var + 1e-5f);
  bf16* o = xn + (size_t)r * D_;
  o[t] = __float2bfloat16((x0 - mean) * rstd * g[t] + bt[t]);
  o[t + 128] = __float2bfloat16((x1 - mean) * rstd * g[t + 128] + bt[t + 128]);
  o[t + 256] = __float2bfloat16((x2 - mean) * rstd * g[t + 256] + bt[t + 256]);
}

// MFMA flash attention. One block per (b, head), 4 waves. Each wave owns
// q-bands {w, w+4, w+8, ...} of 16 rows: QK^T (13 col-tiles, K=64) -> masked
// softmax (band-local, shuffle over l16 only) -> P band to LDS (C->A layout
// round-trip) -> P@V via LDS V^T. No __syncthreads after staging.
__global__ __launch_bounds__(256) void k_attn(const bf16* __restrict__ qkv,
                                              bf16* __restrict__ ctx) {
  const int bh = blockIdx.x;
  const int b = bh / 6, hd = bh % 6;
  const bf16* Qg = qkv + (size_t)b * S_ * 1152 + hd * 64;
  const bf16* Kg = Qg + 384;
  const bf16* Vg = Qg + 768;
  // Vt[d][k] = V[k][d]; stride 232 (116 dw -> 2-way bank alias = free)
  __shared__ __align__(16) __bf16 Vt[64 * 232];
  __shared__ __align__(16) __bf16 Ps[4][16 * 232];
  const int tid = threadIdx.x;
  const int lane = tid & 63, w = tid >> 6;
  const int l16 = lane & 15, quad = lane >> 4;
  const __bf16 z = (__bf16)0.0f;

  // zero Vt pad cols (k = 197..231)
  for (int i = tid; i < 64 * 35; i += 256) {
    int d = i / 35, k = 197 + i % 35;
    Vt[d * 232 + k] = z;
  }
  // stage V transposed
  for (int i = tid; i < S_ * 64; i += 256) {
    int k = i >> 6, d = i & 63;
    Vt[d * 232 + k] = *(const __bf16*)&Vg[(size_t)k * 1152 + d];
  }
  // zero own Ps pad cols (208..231)
  for (int i = lane; i < 16 * 24; i += 64) {
    int r = i / 24, c = 208 + i % 24;
    Ps[w][r * 232 + c] = z;
  }
  __syncthreads();

  const bf16x8 zf = {};
  for (int band = w; band < 13; band += 4) {
    // Q A-fragments (row = band*16 + l16), predicated on row < 197
    const int qrow = band * 16 + l16;
    bf16x8 aq0 = zf, aq1 = zf;
    if (qrow < S_) {
      aq0 = *(const bf16x8*)(Qg + (size_t)qrow * 1152 + quad * 8);
      aq1 = *(const bf16x8*)(Qg + (size_t)qrow * 1152 + 32 + quad * 8);
    }
    // scores: 13 col-tiles of 16
    f32x4 sc[13];
#pragma unroll
    for (int t = 0; t < 13; t++) {
      const int krow = t * 16 + l16;
      bf16x8 bk0 = zf, bk1 = zf;
      if (krow < S_) {
        bk0 = *(const bf16x8*)(Kg + (size_t)krow * 1152 + quad * 8);
        bk1 = *(const bf16x8*)(Kg + (size_t)krow * 1152 + 32 + quad * 8);
      }
      f32x4 a = {};
      a = __builtin_amdgcn_mfma_f32_16x16x32_bf16(aq0, bk0, a, 0, 0, 0);
      a = __builtin_amdgcn_mfma_f32_16x16x32_bf16(aq1, bk1, a, 0, 0, 0);
      sc[t] = a;
    }
    // scale 1/sqrt(64), mask pad cols (192+l16 >= 197)
#pragma unroll
    for (int t = 0; t < 13; t++)
#pragma unroll
      for (int r = 0; r < 4; r++) sc[t][r] *= 0.125f;
    if (l16 >= 5) {
#pragma unroll
      for (int r = 0; r < 4; r++) sc[12][r] = -1e30f;
    }
    // row max (across 13 tiles in-reg, then across the 16 lanes of this quad)
    f32x4 mx = sc[0];
#pragma unroll
    for (int t = 1; t < 13; t++)
#pragma unroll
      for (int r = 0; r < 4; r++) mx[r] = fmaxf(mx[r], sc[t][r]);
#pragma unroll
    for (int o = 1; o < 16; o <<= 1)
#pragma unroll
      for (int r = 0; r < 4; r++) mx[r] = fmaxf(mx[r], __shfl_xor(mx[r], o));
    // exp + row sum
    f32x4 sum = {};
#pragma unroll
    for (int t = 0; t < 13; t++)
#pragma unroll
      for (int r = 0; r < 4; r++) {
        float p = __expf(sc[t][r] - mx[r]);
        sc[t][r] = p;
        sum[r] += p;
      }
#pragma unroll
    for (int o = 1; o < 16; o <<= 1)
#pragma unroll
      for (int r = 0; r < 4; r++) sum[r] += __shfl_xor(sum[r], o);
    f32x4 rinv;
#pragma unroll
    for (int r = 0; r < 4; r++) rinv[r] = 1.0f / sum[r];
    // write unnormalized P band (C layout -> LDS); pad cols 197..207 are
    // exact zeros (exp(-1e30-m) underflows to 0)
#pragma unroll
    for (int t = 0; t < 13; t++)
#pragma unroll
      for (int r = 0; r < 4; r++)
        Ps[w][(quad * 4 + r) * 232 + t * 16 + l16] = (__bf16)sc[t][r];
    // P @ V: out cols d = c*16 + l16, k over 224 (7 steps of 32)
    f32x4 oacc[4] = {};
#pragma unroll
    for (int ks = 0; ks < 7; ks++) {
      bf16x8 pa = *(const bf16x8*)&Ps[w][l16 * 232 + ks * 32 + quad * 8];
#pragma unroll
      for (int c = 0; c < 4; c++) {
        bf16x8 bv = *(const bf16x8*)&Vt[(c * 16 + l16) * 232 + ks * 32 + quad * 8];
        oacc[c] = __builtin_amdgcn_mfma_f32_16x16x32_bf16(pa, bv, oacc[c], 0, 0, 0);
      }
    }
    // epilogue: rows band*16 + quad*4 + r (guarded), cols hd*64 + c*16 + l16
    const int orow = band * 16 + quad * 4;
#pragma unroll
    for (int c = 0; c < 4; c++)
#pragma unroll
      for (int r = 0; r < 4; r++) {
        const int rw = orow + r;
        if (rw < S_)
          ctx[((size_t)b * S_ + rw) * D_ + hd * 64 + c * 16 + l16] =
              __float2bfloat16(oacc[c][r] * rinv[r]);
      }
  }
}

__global__ __launch_bounds__(128) void k_head(const float* __restrict__ h,
                                              const float* __restrict__ g,
                                              const float* __restrict__ bt,
                                              const float* __restrict__ hw,
                                              float* __restrict__ out) {
  const int b = blockIdx.x, t = threadIdx.x;
  const float* row = h + (size_t)b * S_ * D_;
  float x0 = row[t], x1 = row[t + 128], x2 = row[t + 256];
  float s = x0 + x1 + x2;
  float q = x0 * x0 + x1 * x1 + x2 * x2;
#pragma unroll
  for (int o = 32; o; o >>= 1) {
    s += __shfl_xor(s, o);
    q += __shfl_xor(q, o);
  }
  __shared__ float rs[2], rq[2];
  if ((t & 63) == 0) { rs[t >> 6] = s; rq[t >> 6] = q; }
  __syncthreads();
  s = rs[0] + rs[1];
  q = rq[0] + rq[1];
  const float mean = s * (1.f / 384.f);
  const float var = q * (1.f / 384.f) - mean * mean;
  const float rstd = rsqrtf(var + 1e-5f);
  __shared__ float clsn[384];
  clsn[t] = (x0 - mean) * rstd * g[t] + bt[t];
  clsn[t + 128] = (x1 - mean) * rstd * g[t + 128] + bt[t + 128];
  clsn[t + 256] = (x2 - mean) * rstd * g[t + 256] + bt[t + 256];
  __syncthreads();
  if (t < 100) {
    const float* wr = hw + (size_t)t * D_;
    float a = 0.f;
    for (int d = 0; d < 384; d++) a += clsn[d] * wr[d];
    out[b * 100 + t] = a;
  }
}

extern "C" void kernel_launch(void* const* d_in, const int* in_sizes, int n_in,
                              void* d_out, int out_size, void* d_ws, size_t ws_size,
                              hipStream_t stream) {
  (void)in_sizes; (void)n_in; (void)out_size; (void)ws_size;
  const float* x       = (const float*)d_in[0];
  const float* patch_w = (const float*)d_in[1];
  const float* patch_b = (const float*)d_in[2];
  const float* cls_tok = (const float*)d_in[3];
  const float* pos_emb = (const float*)d_in[4];
  const float* ln1_g   = (const float*)d_in[5];
  const float* ln1_b   = (const float*)d_in[6];
  const float* qkv_w   = (const float*)d_in[7];
  const float* qkv_b   = (const float*)d_in[8];
  const float* out_w   = (const float*)d_in[9];
  const float* out_b   = (const float*)d_in[10];
  const float* ln2_g   = (const float*)d_in[11];
  const float* ln2_b   = (const float*)d_in[12];
  const float* fc1_w   = (const float*)d_in[13];
  const float* fc1_b   = (const float*)d_in[14];
  const float* fc2_w   = (const float*)d_in[15];
  const float* fc2_b   = (const float*)d_in[16];
  const float* lnf_g   = (const float*)d_in[17];
  const float* lnf_b   = (const float*)d_in[18];
  const float* head_w  = (const float*)d_in[19];
  float* out = (float*)d_out;

  const size_t R = (size_t)BATCH * S_;  // 25216 token rows
  char* p = (char*)d_ws;
  float* h  = (float*)p; p += R * 384 * 4;       // fp32 residual
  bf16* xn  = (bf16*)p;  p += R * 384 * 2;       // LN output
  bf16* u   = (bf16*)p;  p += R * 1536 * 2;      // union: qkvb|ctxb / hid / patches
  bf16* qkvb = u;                                 // R*1152
  bf16* ctxb = u + R * 1152;                      // R*384
  bf16* hidb = u;                                 // R*1536 (qkv/ctx dead by then)
  bf16* patches = u;                              // 25088*768 (pre-loop only)
  bf16* wb  = (bf16*)p;                           // bf16 weights
  bf16* patch_wb = wb;                            // 768*384
  bf16* qkv_wb   = patch_wb + 294912;             // 12*1152*384
  bf16* out_wb   = qkv_wb + 5308416;              // 12*384*384
  bf16* fc1_wb   = out_wb + 1769472;              // 12*1536*384
  bf16* fc2_wb   = fc1_wb + 7077888;              // 12*384*1536

  // weight conversion fp32 -> bf16 (same work every launch; graph-safe)
  k_f2b<<<dim3((294912 / 4 + 255) / 256), dim3(256), 0, stream>>>(patch_w, patch_wb, 294912 / 4);
  k_f2b<<<dim3((5308416 / 4 + 255) / 256), dim3(256), 0, stream>>>(qkv_w, qkv_wb, 5308416 / 4);
  k_f2b<<<dim3((1769472 / 4 + 255) / 256), dim3(256), 0, stream>>>(out_w, out_wb, 1769472 / 4);
  k_f2b<<<dim3((7077888 / 4 + 255) / 256), dim3(256), 0, stream>>>(fc1_w, fc1_wb, 7077888 / 4);
  k_f2b<<<dim3((7077888 / 4 + 255) / 256), dim3(256), 0, stream>>>(fc2_w, fc2_wb, 7077888 / 4);

  k_embed_init<<<dim3((BATCH * S_ * D_) / 256), dim3(256), 0, stream>>>(cls_tok, pos_emb, h);
  k_patchify<<<dim3((BATCH * 196 * 768) / 256), dim3(256), 0, stream>>>(x, patches);
  // tok = patches @ patch_w^T + patch_b, accumulated into h (row remap b*196+n -> b*197+1+n)
  k_gemm<2><<<dim3(3, 196), dim3(256), 0, stream>>>(patches, patch_wb, patch_b, nullptr, h, 384, 768, 1);

  for (int i = 0; i < 12; i++) {
    k_ln<<<dim3((unsigned)R), dim3(128), 0, stream>>>(h, ln1_g + i * 384, ln1_b + i * 384, xn);
    k_gemm<0><<<dim3(9, 197), dim3(256), 0, stream>>>(xn, qkv_wb + (size_t)i * 1152 * 384,
                                                      qkv_b + i * 1152, qkvb, nullptr, 1152, 384, 0);
    k_attn<<<dim3(768), dim3(256), 0, stream>>>(qkvb, ctxb);
    k_gemm<2><<<dim3(3, 197), dim3(256), 0, stream>>>(ctxb, out_wb + (size_t)i * 384 * 384,
                                                      out_b + i * 384, nullptr, h, 384, 384, 0);
    k_ln<<<dim3((unsigned)R), dim3(128), 0, stream>>>(h, ln2_g + i * 384, ln2_b + i * 384, xn);
    k_gemm<1><<<dim3(12, 197), dim3(256), 0, stream>>>(xn, fc1_wb + (size_t)i * 1536 * 384,
                                                       fc1_b + i * 1536, hidb, nullptr, 1536, 384, 0);
    k_gemm<2><<<dim3(3, 197), dim3(256), 0, stream>>>(hidb, fc2_wb + (size_t)i * 384 * 1536,
                                                      fc2_b + i * 384, nullptr, h, 384, 1536, 0);
  }
  k_head<<<dim3(128), dim3(128), 0, stream>>>(h, lnf_g, lnf_b, head_w, out);
}

// Round 5
// 3700.065 us; speedup vs baseline: 9.2688x; 1.0017x over previous
//
#include <hip/hip_runtime.h>
#include <hip/hip_bf16.h>

// ViT-S/16 forward, B=128. Inputs/outputs fp32 (per reference). Internal:
// weights+activations bf16 for MFMA, residual stream fp32, LN/softmax fp32.
// R5: k_gemm = double-buffered LDS (one barrier/iter, prefetch k+1 during
// compute of k) + XOR chunk-swizzle (kills the 8-way b128 read conflict the
// unpadded async-LDS layout had; swizzle is applied on the GLOBAL source so
// the wave-uniform lane*16B LDS scatter stays legal).

#define S_ 197
#define D_ 384
#define BATCH 128

using bf16 = __hip_bfloat16;
typedef __attribute__((ext_vector_type(8))) __bf16 bf16x8;
typedef __attribute__((ext_vector_type(4))) float f32x4;

#if __has_builtin(__builtin_amdgcn_global_load_lds)
#define HAVE_GLL 1
__device__ __forceinline__ void gll16(const bf16* g, __bf16* l) {
  __builtin_amdgcn_global_load_lds(
      (const __attribute__((address_space(1))) void*)g,
      (__attribute__((address_space(3))) void*)l, 16, 0, 0);
}
#else
#define HAVE_GLL 0
#endif

// fp32 -> bf16 (RN), 4 elements/thread. n must be a multiple of 4.
__global__ __launch_bounds__(256) void k_f2b(const float* __restrict__ src,
                                             bf16* __restrict__ dst, int n4) {
  int i = blockIdx.x * 256 + threadIdx.x;
  if (i >= n4) return;
  float4 v = ((const float4*)src)[i];
  bf16 o[4] = {__float2bfloat16(v.x), __float2bfloat16(v.y),
               __float2bfloat16(v.z), __float2bfloat16(v.w)};
  ((uint2*)dst)[i] = *(uint2*)o;
}

__global__ __launch_bounds__(256) void k_embed_init(const float* __restrict__ cls,
                                                    const float* __restrict__ pos,
                                                    float* __restrict__ h) {
  int idx = blockIdx.x * 256 + threadIdx.x;
  if (idx >= BATCH * S_ * D_) return;
  int d = idx % D_;
  int s = (idx / D_) % S_;
  float v = pos[s * D_ + d];
  if (s == 0) v += cls[d];
  h[idx] = v;
}

__global__ __launch_bounds__(256) void k_patchify(const float* __restrict__ x,
                                                  bf16* __restrict__ patches) {
  int idx = blockIdx.x * 256 + threadIdx.x;
  if (idx >= BATCH * 196 * 768) return;
  int f = idx % 768;
  int n = (idx / 768) % 196;
  int b = idx / (768 * 196);
  int c = f >> 8, rem = f & 255, dy = rem >> 4, dx = rem & 15;
  int py = n / 14, px = n % 14;
  patches[idx] = __float2bfloat16(
      x[(((size_t)b * 3 + c) * 224 + py * 16 + dy) * 224 + px * 16 + dx]);
}

// out[M,N] = X[M,K] @ W[N,K]^T + bias.  Grid: (N/128, M/128), 256 threads.
// MODE 0: out=bf16(v); MODE 1: out=bf16(gelu_exact(v)); MODE 2: res(f32)+=v
// remap!=0 (patch embed): residual row = r + r/196 + 1  (b*196+n -> b*197+1+n)
// LDS layout: row stride 32 elems (64B), 4 chunks of 8 elems per row; slot
// chunk j holds global chunk j ^ ((row>>1)&3)  -> b128 frag reads are 2-way
// bank-aliased (free). Double-buffered: prefetch k+1 while computing k.
template <int MODE>
__global__ __launch_bounds__(256, 4) void k_gemm(const bf16* __restrict__ X,
                                                 const bf16* __restrict__ W,
                                                 const float* __restrict__ bias,
                                                 bf16* __restrict__ out,
                                                 float* __restrict__ res,
                                                 int N, int K, int remap) {
  __shared__ __align__(16) __bf16 As[2][128 * 32];
  __shared__ __align__(16) __bf16 Bs[2][128 * 32];
  const int tid = threadIdx.x;
  const int m0 = blockIdx.y * 128, n0 = blockIdx.x * 128;
  const int lane = tid & 63, w = tid >> 6;
  const int wr = w >> 1, wc = w & 1;
  const int l16 = lane & 15, quad = lane >> 4;
  f32x4 acc[4][4] = {};

  // staging: wave w covers tile rows w*32..w*32+31; 2 gll16 per matrix.
  // lane -> slot row (lane>>2), slot chunk (lane&3); global chunk swizzled:
  // c = (lane&3) ^ ((lane>>3)&3)   [ == (lane&3) ^ ((r>>1)&3) for r=w*32+t*16+(lane>>2) ]
  const int srow = w * 32 + (lane >> 2);
  const int scol = (((lane & 3) ^ ((lane >> 3) & 3)) << 3);
  const bf16* Ag = X + (size_t)(m0 + srow) * K + scol;
  const bf16* Bg = W + (size_t)(n0 + srow) * K + scol;
  const int ldsW = w * 32 * 32;  // wave-uniform LDS base offset (elems)

  // fragment read offsets: row r needs global chunk `quad`, stored at slot
  // chunk quad ^ ((l16>>1)&3)  [ (r>>1)&3 == (l16>>1)&3 since r-l16 is mult of 16 ]
  const int jx8 = ((quad ^ ((l16 >> 1) & 3)) << 3);
  const int aoff = (wr * 64 + l16) * 32 + jx8;
  const int boff = (wc * 64 + l16) * 32 + jx8;

#if HAVE_GLL
#define STAGE(buf, k0)                                         \
  do {                                                         \
    gll16(Ag + (k0), &As[buf][ldsW]);                          \
    gll16(Ag + (k0) + (size_t)16 * K, &As[buf][ldsW + 512]);   \
    gll16(Bg + (k0), &Bs[buf][ldsW]);                          \
    gll16(Bg + (k0) + (size_t)16 * K, &Bs[buf][ldsW + 512]);   \
  } while (0)
#else
#define STAGE(buf, k0)                                                        \
  do {                                                                        \
    *(uint4*)(&As[buf][ldsW + (lane >> 2) * 32 + (lane & 3) * 8]) =           \
        *(const uint4*)(Ag + (k0));                                           \
    *(uint4*)(&As[buf][ldsW + 512 + (lane >> 2) * 32 + (lane & 3) * 8]) =     \
        *(const uint4*)(Ag + (k0) + (size_t)16 * K);                          \
    *(uint4*)(&Bs[buf][ldsW + (lane >> 2) * 32 + (lane & 3) * 8]) =           \
        *(const uint4*)(Bg + (k0));                                           \
    *(uint4*)(&Bs[buf][ldsW + 512 + (lane >> 2) * 32 + (lane & 3) * 8]) =     \
        *(const uint4*)(Bg + (k0) + (size_t)16 * K);                          \
  } while (0)
#endif

  STAGE(0, 0);
  __syncthreads();
  for (int k0 = 0; k0 < K; k0 += 32) {
    const int cb = (k0 >> 5) & 1;
    if (k0 + 32 < K) STAGE(cb ^ 1, k0 + 32);
    bf16x8 av[4], bv[4];
#pragma unroll
    for (int i = 0; i < 4; i++)
      av[i] = *(const bf16x8*)(&As[cb][aoff + i * 512]);
#pragma unroll
    for (int j = 0; j < 4; j++)
      bv[j] = *(const bf16x8*)(&Bs[cb][boff + j * 512]);
#pragma unroll
    for (int i = 0; i < 4; i++)
#pragma unroll
      for (int j = 0; j < 4; j++)
        acc[i][j] = __builtin_amdgcn_mfma_f32_16x16x32_bf16(av[i], bv[j], acc[i][j], 0, 0, 0);
    __syncthreads();
  }
#undef STAGE

  float bvv[4];
#pragma unroll
  for (int j = 0; j < 4; j++)
    bvv[j] = bias[n0 + wc * 64 + j * 16 + l16];
#pragma unroll
  for (int i = 0; i < 4; i++) {
    const int rbase = m0 + wr * 64 + i * 16 + quad * 4;
#pragma unroll
    for (int j = 0; j < 4; j++) {
      const int col = n0 + wc * 64 + j * 16 + l16;
#pragma unroll
      for (int r = 0; r < 4; r++) {
        float v = acc[i][j][r] + bvv[j];
        int rw = rbase + r;
        if (MODE == 0) {
          out[(size_t)rw * N + col] = __float2bfloat16(v);
        } else if (MODE == 1) {
          float gl = 0.5f * v * (1.f + erff(v * 0.70710678118f));
          out[(size_t)rw * N + col] = __float2bfloat16(gl);
        } else {
          int hr = remap ? (rw + rw / 196 + 1) : rw;
          res[(size_t)hr * N + col] += v;
        }
      }
    }
  }
}

__global__ __launch_bounds__(128) void k_ln(const float* __restrict__ h,
                                            const float* __restrict__ g,
                                            const float* __restrict__ bt,
                                            bf16* __restrict__ xn) {
  const int r = blockIdx.x, t = threadIdx.x;
  const float* row = h + (size_t)r * D_;
  float x0 = row[t], x1 = row[t + 128], x2 = row[t + 256];
  float s = x0 + x1 + x2;
  float q = x0 * x0 + x1 * x1 + x2 * x2;
#pragma unroll
  for (int o = 32; o; o >>= 1) {
    s += __shfl_xor(s, o);
    q += __shfl_xor(q, o);
  }
  __shared__ float rs[2], rq[2];
  if ((t & 63) == 0) { rs[t >> 6] = s; rq[t >> 6] = q; }
  __syncthreads();
  s = rs[0] + rs[1];
  q = rq[0] + rq[1];
  const float mean = s * (1.f / 384.f);
  const float var = q * (1.f / 384.f) - mean * mean;
  const float rstd = rsqrtf(var + 1e-5f);
  bf16* o = xn + (size_t)r * D_;
  o[t] = __float2bfloat16((x0 - mean) * rstd * g[t] + bt[t]);
  o[t + 128] = __float2bfloat16((x1 - mean) * rstd * g[t + 128] + bt[t + 128]);
  o[t + 256] = __float2bfloat16((x2 - mean) * rstd * g[t + 256] + bt[t + 256]);
}

// MFMA flash attention. One block per (b, head), 4 waves. Each wave owns
// q-bands {w, w+4, w+8, ...} of 16 rows: QK^T (13 col-tiles, K=64) -> masked
// softmax (band-local, shuffle over l16 only) -> P band to LDS (C->A layout
// round-trip) -> P@V via LDS V^T. No __syncthreads after staging.
__global__ __launch_bounds__(256) void k_attn(const bf16* __restrict__ qkv,
                                              bf16* __restrict__ ctx) {
  const int bh = blockIdx.x;
  const int b = bh / 6, hd = bh % 6;
  const bf16* Qg = qkv + (size_t)b * S_ * 1152 + hd * 64;
  const bf16* Kg = Qg + 384;
  const bf16* Vg = Qg + 768;
  // Vt[d][k] = V[k][d]; stride 232 (116 dw -> 2-way bank alias = free)
  __shared__ __align__(16) __bf16 Vt[64 * 232];
  __shared__ __align__(16) __bf16 Ps[4][16 * 232];
  const int tid = threadIdx.x;
  const int lane = tid & 63, w = tid >> 6;
  const int l16 = lane & 15, quad = lane >> 4;
  const __bf16 z = (__bf16)0.0f;

  // zero Vt pad cols (k = 197..231)
  for (int i = tid; i < 64 * 35; i += 256) {
    int d = i / 35, k = 197 + i % 35;
    Vt[d * 232 + k] = z;
  }
  // stage V transposed
  for (int i = tid; i < S_ * 64; i += 256) {
    int k = i >> 6, d = i & 63;
    Vt[d * 232 + k] = *(const __bf16*)&Vg[(size_t)k * 1152 + d];
  }
  // zero own Ps pad cols (208..231)
  for (int i = lane; i < 16 * 24; i += 64) {
    int r = i / 24, c = 208 + i % 24;
    Ps[w][r * 232 + c] = z;
  }
  __syncthreads();

  const bf16x8 zf = {};
  for (int band = w; band < 13; band += 4) {
    // Q A-fragments (row = band*16 + l16), predicated on row < 197
    const int qrow = band * 16 + l16;
    bf16x8 aq0 = zf, aq1 = zf;
    if (qrow < S_) {
      aq0 = *(const bf16x8*)(Qg + (size_t)qrow * 1152 + quad * 8);
      aq1 = *(const bf16x8*)(Qg + (size_t)qrow * 1152 + 32 + quad * 8);
    }
    // scores: 13 col-tiles of 16
    f32x4 sc[13];
#pragma unroll
    for (int t = 0; t < 13; t++) {
      const int krow = t * 16 + l16;
      bf16x8 bk0 = zf, bk1 = zf;
      if (krow < S_) {
        bk0 = *(const bf16x8*)(Kg + (size_t)krow * 1152 + quad * 8);
        bk1 = *(const bf16x8*)(Kg + (size_t)krow * 1152 + 32 + quad * 8);
      }
      f32x4 a = {};
      a = __builtin_amdgcn_mfma_f32_16x16x32_bf16(aq0, bk0, a, 0, 0, 0);
      a = __builtin_amdgcn_mfma_f32_16x16x32_bf16(aq1, bk1, a, 0, 0, 0);
      sc[t] = a;
    }
    // scale 1/sqrt(64), mask pad cols (192+l16 >= 197)
#pragma unroll
    for (int t = 0; t < 13; t++)
#pragma unroll
      for (int r = 0; r < 4; r++) sc[t][r] *= 0.125f;
    if (l16 >= 5) {
#pragma unroll
      for (int r = 0; r < 4; r++) sc[12][r] = -1e30f;
    }
    // row max (across 13 tiles in-reg, then across the 16 lanes of this quad)
    f32x4 mx = sc[0];
#pragma unroll
    for (int t = 1; t < 13; t++)
#pragma unroll
      for (int r = 0; r < 4; r++) mx[r] = fmaxf(mx[r], sc[t][r]);
#pragma unroll
    for (int o = 1; o < 16; o <<= 1)
#pragma unroll
      for (int r = 0; r < 4; r++) mx[r] = fmaxf(mx[r], __shfl_xor(mx[r], o));
    // exp + row sum
    f32x4 sum = {};
#pragma unroll
    for (int t = 0; t < 13; t++)
#pragma unroll
      for (int r = 0; r < 4; r++) {
        float p = __expf(sc[t][r] - mx[r]);
        sc[t][r] = p;
        sum[r] += p;
      }
#pragma unroll
    for (int o = 1; o < 16; o <<= 1)
#pragma unroll
      for (int r = 0; r < 4; r++) sum[r] += __shfl_xor(sum[r], o);
    f32x4 rinv;
#pragma unroll
    for (int r = 0; r < 4; r++) rinv[r] = 1.0f / sum[r];
    // write unnormalized P band (C layout -> LDS); pad cols 197..207 are
    // exact zeros (exp(-1e30-m) underflows to 0)
#pragma unroll
    for (int t = 0; t < 13; t++)
#pragma unroll
      for (int r = 0; r < 4; r++)
        Ps[w][(quad * 4 + r) * 232 + t * 16 + l16] = (__bf16)sc[t][r];
    // P @ V: out cols d = c*16 + l16, k over 224 (7 steps of 32)
    f32x4 oacc[4] = {};
#pragma unroll
    for (int ks = 0; ks < 7; ks++) {
      bf16x8 pa = *(const bf16x8*)&Ps[w][l16 * 232 + ks * 32 + quad * 8];
#pragma unroll
      for (int c = 0; c < 4; c++) {
        bf16x8 bv = *(const bf16x8*)&Vt[(c * 16 + l16) * 232 + ks * 32 + quad * 8];
        oacc[c] = __builtin_amdgcn_mfma_f32_16x16x32_bf16(pa, bv, oacc[c], 0, 0, 0);
      }
    }
    // epilogue: rows band*16 + quad*4 + r (guarded), cols hd*64 + c*16 + l16
    const int orow = band * 16 + quad * 4;
#pragma unroll
    for (int c = 0; c < 4; c++)
#pragma unroll
      for (int r = 0; r < 4; r++) {
        const int rw = orow + r;
        if (rw < S_)
          ctx[((size_t)b * S_ + rw) * D_ + hd * 64 + c * 16 + l16] =
              __float2bfloat16(oacc[c][r] * rinv[r]);
      }
  }
}

__global__ __launch_bounds__(128) void k_head(const float* __restrict__ h,
                                              const float* __restrict__ g,
                                              const float* __restrict__ bt,
                                              const float* __restrict__ hw,
                                              float* __restrict__ out) {
  const int b = blockIdx.x, t = threadIdx.x;
  const float* row = h + (size_t)b * S_ * D_;
  float x0 = row[t], x1 = row[t + 128], x2 = row[t + 256];
  float s = x0 + x1 + x2;
  float q = x0 * x0 + x1 * x1 + x2 * x2;
#pragma unroll
  for (int o = 32; o; o >>= 1) {
    s += __shfl_xor(s, o);
    q += __shfl_xor(q, o);
  }
  __shared__ float rs[2], rq[2];
  if ((t & 63) == 0) { rs[t >> 6] = s; rq[t >> 6] = q; }
  __syncthreads();
  s = rs[0] + rs[1];
  q = rq[0] + rq[1];
  const float mean = s * (1.f / 384.f);
  const float var = q * (1.f / 384.f) - mean * mean;
  const float rstd = rsqrtf(var + 1e-5f);
  __shared__ float clsn[384];
  clsn[t] = (x0 - mean) * rstd * g[t] + bt[t];
  clsn[t + 128] = (x1 - mean) * rstd * g[t + 128] + bt[t + 128];
  clsn[t + 256] = (x2 - mean) * rstd * g[t + 256] + bt[t + 256];
  __syncthreads();
  if (t < 100) {
    const float* wr = hw + (size_t)t * D_;
    float a = 0.f;
    for (int d = 0; d < 384; d++) a += clsn[d] * wr[d];
    out[b * 100 + t] = a;
  }
}

extern "C" void kernel_launch(void* const* d_in, const int* in_sizes, int n_in,
                              void* d_out, int out_size, void* d_ws, size_t ws_size,
                              hipStream_t stream) {
  (void)in_sizes; (void)n_in; (void)out_size; (void)ws_size;
  const float* x       = (const float*)d_in[0];
  const float* patch_w = (const float*)d_in[1];
  const float* patch_b = (const float*)d_in[2];
  const float* cls_tok = (const float*)d_in[3];
  const float* pos_emb = (const float*)d_in[4];
  const float* ln1_g   = (const float*)d_in[5];
  const float* ln1_b   = (const float*)d_in[6];
  const float* qkv_w   = (const float*)d_in[7];
  const float* qkv_b   = (const float*)d_in[8];
  const float* out_w   = (const float*)d_in[9];
  const float* out_b   = (const float*)d_in[10];
  const float* ln2_g   = (const float*)d_in[11];
  const float* ln2_b   = (const float*)d_in[12];
  const float* fc1_w   = (const float*)d_in[13];
  const float* fc1_b   = (const float*)d_in[14];
  const float* fc2_w   = (const float*)d_in[15];
  const float* fc2_b   = (const float*)d_in[16];
  const float* lnf_g   = (const float*)d_in[17];
  const float* lnf_b   = (const float*)d_in[18];
  const float* head_w  = (const float*)d_in[19];
  float* out = (float*)d_out;

  const size_t R = (size_t)BATCH * S_;  // 25216 token rows
  char* p = (char*)d_ws;
  float* h  = (float*)p; p += R * 384 * 4;       // fp32 residual
  bf16* xn  = (bf16*)p;  p += R * 384 * 2;       // LN output
  bf16* u   = (bf16*)p;  p += R * 1536 * 2;      // union: qkvb|ctxb / hid / patches
  bf16* qkvb = u;                                 // R*1152
  bf16* ctxb = u + R * 1152;                      // R*384
  bf16* hidb = u;                                 // R*1536 (qkv/ctx dead by then)
  bf16* patches = u;                              // 25088*768 (pre-loop only)
  bf16* wb  = (bf16*)p;                           // bf16 weights
  bf16* patch_wb = wb;                            // 768*384
  bf16* qkv_wb   = patch_wb + 294912;             // 12*1152*384
  bf16* out_wb   = qkv_wb + 5308416;              // 12*384*384
  bf16* fc1_wb   = out_wb + 1769472;              // 12*1536*384
  bf16* fc2_wb   = fc1_wb + 7077888;              // 12*384*1536

  // weight conversion fp32 -> bf16 (same work every launch; graph-safe)
  k_f2b<<<dim3((294912 / 4 + 255) / 256), dim3(256), 0, stream>>>(patch_w, patch_wb, 294912 / 4);
  k_f2b<<<dim3((5308416 / 4 + 255) / 256), dim3(256), 0, stream>>>(qkv_w, qkv_wb, 5308416 / 4);
  k_f2b<<<dim3((1769472 / 4 + 255) / 256), dim3(256), 0, stream>>>(out_w, out_wb, 1769472 / 4);
  k_f2b<<<dim3((7077888 / 4 + 255) / 256), dim3(256), 0, stream>>>(fc1_w, fc1_wb, 7077888 / 4);
  k_f2b<<<dim3((7077888 / 4 + 255) / 256), dim3(256), 0, stream>>>(fc2_w, fc2_wb, 7077888 / 4);

  k_embed_init<<<dim3((BATCH * S_ * D_) / 256), dim3(256), 0, stream>>>(cls_tok, pos_emb, h);
  k_patchify<<<dim3((BATCH * 196 * 768) / 256), dim3(256), 0, stream>>>(x, patches);
  // tok = patches @ patch_w^T + patch_b, accumulated into h (row remap b*196+n -> b*197+1+n)
  k_gemm<2><<<dim3(3, 196), dim3(256), 0, stream>>>(patches, patch_wb, patch_b, nullptr, h, 384, 768, 1);

  for (int i = 0; i < 12; i++) {
    k_ln<<<dim3((unsigned)R), dim3(128), 0, stream>>>(h, ln1_g + i * 384, ln1_b + i * 384, xn);
    k_gemm<0><<<dim3(9, 197), dim3(256), 0, stream>>>(xn, qkv_wb + (size_t)i * 1152 * 384,
                                                      qkv_b + i * 1152, qkvb, nullptr, 1152, 384, 0);
    k_attn<<<dim3(768), dim3(256), 0, stream>>>(qkvb, ctxb);
    k_gemm<2><<<dim3(3, 197), dim3(256), 0, stream>>>(ctxb, out_wb + (size_t)i * 384 * 384,
                                                      out_b + i * 384, nullptr, h, 384, 384, 0);
    k_ln<<<dim3((unsigned)R), dim3(128), 0, stream>>>(h, ln2_g + i * 384, ln2_b + i * 384, xn);
    k_gemm<1><<<dim3(12, 197), dim3(256), 0, stream>>>(xn, fc1_wb + (size_t)i * 1536 * 384,
                                                       fc1_b + i * 1536, hidb, nullptr, 1536, 384, 0);
    k_gemm<2><<<dim3(3, 197), dim3(256), 0, stream>>>(hidb, fc2_wb + (size_t)i * 384 * 1536,
                                                      fc2_b + i * 384, nullptr, h, 384, 1536, 0);
  }
  k_head<<<dim3(128), dim3(128), 0, stream>>>(h, lnf_g, lnf_b, head_w, out);
}